// Round 1
// baseline (1238.327 us; speedup 1.0000x reference)
//
#include <hip/hip_runtime.h>

// CosFace: out = logits * S, with out[r, labels[r]] = (logits[r, labels[r]] - M) * S
// for rows where labels[r] != -1.
// logits: [4096, 50257] f32, labels: [4096] int. Pure HBM-bound elementwise.

#define S_SCALE 64.0f
#define MARGIN  0.35f
#define BATCH   4096
#define NUM_CLASSES 50257
// total = 4096 * 50257 = 205852672, divisible by 4.
#define TOTAL_ELEMS (205852672LL)
#define TOTAL_VEC4  (TOTAL_ELEMS / 4)

__global__ __launch_bounds__(256) void scale_kernel(const float4* __restrict__ in,
                                                    float4* __restrict__ out,
                                                    long long n4) {
    long long i = (long long)blockIdx.x * blockDim.x + threadIdx.x;
    if (i < n4) {
        float4 v = in[i];
        v.x *= S_SCALE; v.y *= S_SCALE; v.z *= S_SCALE; v.w *= S_SCALE;
        out[i] = v;
    }
}

__global__ __launch_bounds__(256) void fixup_kernel(const float* __restrict__ logits,
                                                    const int* __restrict__ labels,
                                                    float* __restrict__ out) {
    int r = blockIdx.x * blockDim.x + threadIdx.x;
    if (r < BATCH) {
        int lab = labels[r];
        if (lab != -1) {
            long long idx = (long long)r * NUM_CLASSES + lab;
            out[idx] = (logits[idx] - MARGIN) * S_SCALE;
        }
    }
}

extern "C" void kernel_launch(void* const* d_in, const int* in_sizes, int n_in,
                              void* d_out, int out_size, void* d_ws, size_t ws_size,
                              hipStream_t stream) {
    const float* logits = (const float*)d_in[0];
    const int* labels = (const int*)d_in[1];
    float* out = (float*)d_out;

    long long n4 = TOTAL_VEC4;
    int threads = 256;
    long long blocks = (n4 + threads - 1) / threads;
    scale_kernel<<<(unsigned int)blocks, threads, 0, stream>>>(
        (const float4*)logits, (float4*)out, n4);

    fixup_kernel<<<(BATCH + 255) / 256, 256, 0, stream>>>(logits, labels, out);
}